// Round 19
// baseline (206.260 us; speedup 1.0000x reference)
//
#include <hip/hip_runtime.h>

#define SENT32 0x7FFFFFFF
#define IDMASK 0x1FFFF
#define RSHIFT 17
#define NLEVELS 5
#define POOLM 16

// block-wide allocation: per-thread cnt -> contiguous base in *gctr.
__device__ __forceinline__ int block_alloc(int cnt, int* gctr, int* lds) {
    int lane = threadIdx.x & 63, wid = threadIdx.x >> 6;
    int pfx = cnt;
#pragma unroll
    for (int off = 1; off < 64; off <<= 1) {
        int t = __shfl_up(pfx, off, 64);
        if (lane >= off) pfx += t;
    }
    if (lane == 63) lds[wid] = pfx;
    __syncthreads();
    if (threadIdx.x == 0) {
        int t = lds[0] + lds[1] + lds[2] + lds[3];
        int bse = t ? atomicAdd(gctr, t) : 0;
        lds[4] = bse;
        lds[5] = bse + lds[0];
        lds[6] = lds[5] + lds[1];
        lds[7] = lds[6] + lds[2];
    }
    __syncthreads();
    return lds[4 + wid] + pfx - cnt;
}

// ---- 1. elevation: elev = x @ W + b, f64 accumulation, wave-per-row ----
__global__ __launch_bounds__(256) void k_matvec(const float* __restrict__ x,
                                                const float* __restrict__ W,
                                                const float* __restrict__ b,
                                                double* __restrict__ elev64,
                                                float* __restrict__ elev32,
                                                int N, int C) {
    int lane = threadIdx.x & 63;
    int wib  = threadIdx.x >> 6;
    int row  = blockIdx.x * (blockDim.x >> 6) + wib;
    if (row >= N) return;
    const float* xr = x + (size_t)row * C;
    double s = 0.0;
    for (int c = lane; c < C; c += 64) s += (double)xr[c] * (double)W[c];
#pragma unroll
    for (int off = 32; off > 0; off >>= 1) s += __shfl_down(s, off, 64);
    if (lane == 0) {
        double v = s + (double)b[0];
        elev64[row] = v;
        elev32[row] = (float)v;
    }
}

// ---- 2. mark pass, 4 pairs/thread. f32 compare with f64 fallback on ties ----
__global__ __launch_bounds__(256) void k_mark(const int* __restrict__ ei,
                                              const double* __restrict__ elev64,
                                              const float* __restrict__ elev32,
                                              unsigned char* __restrict__ notpeak,
                                              unsigned char* __restrict__ nottrough,
                                              unsigned char* __restrict__ code,
                                              int Eh, int E) {
    int t0 = (blockIdx.x * 256 + threadIdx.x) * 4;
    if (t0 >= Eh) return;
    bool v0 = true, v1 = (t0 + 1 < Eh), v2 = (t0 + 2 < Eh), v3 = (t0 + 3 < Eh);
    int s0 = 0, s1 = 0, s2 = 0, s3 = 0, d0 = 0, d1 = 0, d2 = 0, d3 = 0;
    if (v3) {
        int4 sv = *(const int4*)&ei[t0];
        int4 dv = *(const int4*)&ei[(size_t)E + t0];
        s0 = sv.x; s1 = sv.y; s2 = sv.z; s3 = sv.w;
        d0 = dv.x; d1 = dv.y; d2 = dv.z; d3 = dv.w;
    } else {
        s0 = ei[t0];            d0 = ei[(size_t)E + t0];
        if (v1) { s1 = ei[t0 + 1]; d1 = ei[(size_t)E + t0 + 1]; }
        if (v2) { s2 = ei[t0 + 2]; d2 = ei[(size_t)E + t0 + 2]; }
    }
    float fs0 = elev32[s0], fs1 = elev32[s1], fs2 = elev32[s2], fs3 = elev32[s3];
    float fd0 = elev32[d0], fd1 = elev32[d1], fd2 = elev32[d2], fd3 = elev32[d3];
    unsigned cw = 0;
#define MARK1(J, VV, SS, DD, FS, FD)                                          \
    if (VV) {                                                                 \
        unsigned c;                                                           \
        if (FD < FS)      { notpeak[DD] = 1; nottrough[SS] = 1; c = 1u; }     \
        else if (FD > FS) { notpeak[SS] = 1; nottrough[DD] = 1; c = 2u; }     \
        else {                                                                \
            double ax = elev64[SS], bx = elev64[DD];                          \
            if (bx < ax)      { notpeak[DD] = 1; nottrough[SS] = 1; c = 1u; } \
            else if (bx > ax) { notpeak[SS] = 1; nottrough[DD] = 1; c = 2u; } \
            else c = 3u;                                                      \
        }                                                                     \
        cw |= c << (8 * J);                                                   \
    }
    MARK1(0, v0, s0, d0, fs0, fd0)
    MARK1(1, v1, s1, d1, fs1, fd1)
    MARK1(2, v2, s2, d2, fs2, fd2)
    MARK1(3, v3, s3, d3, fs3, fd3)
#undef MARK1
    if (v3) {
        *(unsigned*)&code[t0] = cw;
    } else {
        code[t0] = (unsigned char)(cw & 0xFF);
        if (v1) code[t0 + 1] = (unsigned char)((cw >> 8) & 0xFF);
        if (v2) code[t0 + 2] = (unsigned char)((cw >> 16) & 0xFF);
    }
}

// ---- 3. node pass: flags, best/rnd init, per-block peak partials ----
__global__ __launch_bounds__(256) void k_nodes1(const unsigned char* __restrict__ notpeak,
                                                const unsigned char* __restrict__ nottrough,
                                                int* __restrict__ peakflag,
                                                int* __restrict__ best,
                                                unsigned char* __restrict__ rnd,
                                                float* __restrict__ out_ispeak,
                                                float* __restrict__ out_istrough,
                                                float* __restrict__ out_cb,
                                                int* __restrict__ part, int N) {
    __shared__ int ws[4];
    int n = blockIdx.x * 256 + threadIdx.x;
    int lane = threadIdx.x & 63, wid = threadIdx.x >> 6;
    int pk = 0;
    if (n < N) {
        pk = notpeak[n] ? 0 : 1;
        int tr = nottrough[n] ? 0 : 1;
        peakflag[n] = pk;
        out_ispeak[n] = (float)pk;
        out_istrough[n] = (float)tr;
        best[n] = pk ? n : SENT32;
        rnd[n] = pk ? 0 : 0xFF;
        out_cb[n] = -1.0f;
    }
    unsigned long long mk = __ballot(pk);
    if (lane == 0) ws[wid] = __popcll(mk);
    __syncthreads();
    if (threadIdx.x == 0) part[blockIdx.x] = ws[0] + ws[1] + ws[2] + ws[3];
}

// ---- 4. scan helpers ----
__global__ __launch_bounds__(64) void k_scan_offs(const int* __restrict__ part,
                                                  int* __restrict__ offs, int P) {
    int lane = threadIdx.x;
    int chunk = (P + 63) / 64;
    int s0 = lane * chunk, s1 = min(s0 + chunk, P);
    int s = 0;
    for (int j = s0; j < s1; ++j) s += part[j];
    int incl = s;
#pragma unroll
    for (int off = 1; off < 64; off <<= 1) {
        int t = __shfl_up(incl, off, 64);
        if (lane >= off) incl += t;
    }
    int run = incl - s;
    for (int j = s0; j < s1; ++j) { offs[j] = run; run += part[j]; }
}

// new_id = inclusive_scan(peakflag)-1; fused: bsnap + rnd2 snapshot + K
__global__ __launch_bounds__(256) void k_scan_final0(const int* __restrict__ flag,
                                                     const int* __restrict__ offs,
                                                     const int* __restrict__ best,
                                                     const unsigned char* __restrict__ rnd,
                                                     int* __restrict__ new_id,
                                                     int* __restrict__ bsnap,
                                                     unsigned char* __restrict__ rnd2,
                                                     int* __restrict__ Kptr, int N) {
    __shared__ int tmp[256];
    int n = blockIdx.x * 256 + threadIdx.x;
    int f = (n < N) ? flag[n] : 0;
    tmp[threadIdx.x] = f;
    __syncthreads();
    for (int off = 1; off < 256; off <<= 1) {
        int t = (threadIdx.x >= off) ? tmp[threadIdx.x - off] : 0;
        __syncthreads();
        tmp[threadIdx.x] += t;
        __syncthreads();
    }
    if (n < N) {
        int incl = offs[blockIdx.x] + tmp[threadIdx.x];
        new_id[n] = incl - 1;
        bsnap[n] = best[n];
        rnd2[n] = rnd[n];
        if (n == N - 1) Kptr[0] = incl;
    }
}

// ---- 5a. BFS level 1: streaming relax, 8 pairs/thread ----
__global__ __launch_bounds__(256) void k_build_l1(const int* __restrict__ ei,
                                                  const unsigned char* __restrict__ code,
                                                  const unsigned char* __restrict__ notpeak,
                                                  int* __restrict__ best,
                                                  unsigned char* __restrict__ rnd,
                                                  int Eh, int E) {
    int t0 = (blockIdx.x * 256 + threadIdx.x) * 8;
    if (t0 >= Eh) return;
    int s0=0,s1=0,s2=0,s3=0,s4=0,s5=0,s6=0,s7=0;
    int d0=0,d1=0,d2=0,d3=0,d4=0,d5=0,d6=0,d7=0;
    unsigned cwA = 0, cwB = 0;
    if (t0 + 8 <= Eh) {
        int4 sa = *(const int4*)&ei[t0];
        int4 sb = *(const int4*)&ei[t0 + 4];
        int4 da = *(const int4*)&ei[(size_t)E + t0];
        int4 db = *(const int4*)&ei[(size_t)E + t0 + 4];
        s0=sa.x;s1=sa.y;s2=sa.z;s3=sa.w; s4=sb.x;s5=sb.y;s6=sb.z;s7=sb.w;
        d0=da.x;d1=da.y;d2=da.z;d3=da.w; d4=db.x;d5=db.y;d6=db.z;d7=db.w;
        cwA = *(const unsigned*)&code[t0];
        cwB = *(const unsigned*)&code[t0 + 4];
    } else {
        if (t0+0<Eh){s0=ei[t0+0];d0=ei[(size_t)E+t0+0];cwA|=(unsigned)code[t0+0];}
        if (t0+1<Eh){s1=ei[t0+1];d1=ei[(size_t)E+t0+1];cwA|=(unsigned)code[t0+1]<<8;}
        if (t0+2<Eh){s2=ei[t0+2];d2=ei[(size_t)E+t0+2];cwA|=(unsigned)code[t0+2]<<16;}
        if (t0+3<Eh){s3=ei[t0+3];d3=ei[(size_t)E+t0+3];cwA|=(unsigned)code[t0+3]<<24;}
        if (t0+4<Eh){s4=ei[t0+4];d4=ei[(size_t)E+t0+4];cwB|=(unsigned)code[t0+4];}
        if (t0+5<Eh){s5=ei[t0+5];d5=ei[(size_t)E+t0+5];cwB|=(unsigned)code[t0+5]<<8;}
        if (t0+6<Eh){s6=ei[t0+6];d6=ei[(size_t)E+t0+6];cwB|=(unsigned)code[t0+6]<<16;}
    }
    bool w0=(t0+0<Eh),w1=(t0+1<Eh),w2=(t0+2<Eh),w3=(t0+3<Eh);
    bool w4=(t0+4<Eh),w5=(t0+5<Eh),w6=(t0+6<Eh),w7=(t0+7<Eh);
    unsigned char nps0=notpeak[s0],nps1=notpeak[s1],nps2=notpeak[s2],nps3=notpeak[s3];
    unsigned char nps4=notpeak[s4],nps5=notpeak[s5],nps6=notpeak[s6],nps7=notpeak[s7];
    unsigned char npd0=notpeak[d0],npd1=notpeak[d1],npd2=notpeak[d2],npd3=notpeak[d3];
    unsigned char npd4=notpeak[d4],npd5=notpeak[d5],npd6=notpeak[d6],npd7=notpeak[d7];
#define BUILD1(CW, J, VV, SS, DD, NPS, NPD)                                   \
    if (VV) {                                                                 \
        unsigned cd = (CW >> (8 * J)) & 0xFFu;                                \
        bool ps = !NPS, pd = !NPD;                                            \
        if ((cd & 1u) && ps && !pd) {                                         \
            int old = atomicMin(&best[DD], (1 << RSHIFT) | SS);               \
            if (old == SENT32) rnd[DD] = 1;                                   \
        }                                                                     \
        if ((cd & 2u) && pd && !ps) {                                         \
            int old = atomicMin(&best[SS], (1 << RSHIFT) | DD);               \
            if (old == SENT32) rnd[SS] = 1;                                   \
        }                                                                     \
    }
    BUILD1(cwA, 0, w0, s0, d0, nps0, npd0)
    BUILD1(cwA, 1, w1, s1, d1, nps1, npd1)
    BUILD1(cwA, 2, w2, s2, d2, nps2, npd2)
    BUILD1(cwA, 3, w3, s3, d3, nps3, npd3)
    BUILD1(cwB, 0, w4, s4, d4, nps4, npd4)
    BUILD1(cwB, 1, w5, s5, d5, nps5, npd5)
    BUILD1(cwB, 2, w6, s6, d6, nps6, npd6)
    BUILD1(cwB, 3, w7, s7, d7, nps7, npd7)
#undef BUILD1
}

// ---- 5b. BFS level 2: re-stream ei/code; READ rnd2 snapshot (clean,
// never written this kernel -> no cross-XCD line thrash), WRITE live rnd.
// Snapshot semantics exact for frontier (round-1 final); stale rd==0xFF
// only adds an atomicMin (arbitrated correctly) or a kept edge (filtered
// at L3) -- both within established race-safety. ----
__global__ __launch_bounds__(256) void k_sweep2(const int* __restrict__ ei,
                                                const unsigned char* __restrict__ code,
                                                const int* __restrict__ bsnap,
                                                const unsigned char* __restrict__ rnd2,
                                                int* __restrict__ best,
                                                unsigned char* __restrict__ rnd,
                                                int2* __restrict__ dst,
                                                int* __restrict__ dcnt,
                                                int Eh, int E) {
    __shared__ int lds[8];
    int t0 = (blockIdx.x * 256 + threadIdx.x) * 8;
    int s0=0,s1=0,s2=0,s3=0,s4=0,s5=0,s6=0,s7=0;
    int d0=0,d1=0,d2=0,d3=0,d4=0,d5=0,d6=0,d7=0;
    unsigned cwA = 0, cwB = 0;
    if (t0 + 8 <= Eh) {
        int4 sa = *(const int4*)&ei[t0];
        int4 sb = *(const int4*)&ei[t0 + 4];
        int4 da = *(const int4*)&ei[(size_t)E + t0];
        int4 db = *(const int4*)&ei[(size_t)E + t0 + 4];
        s0=sa.x;s1=sa.y;s2=sa.z;s3=sa.w; s4=sb.x;s5=sb.y;s6=sb.z;s7=sb.w;
        d0=da.x;d1=da.y;d2=da.z;d3=da.w; d4=db.x;d5=db.y;d6=db.z;d7=db.w;
        cwA = *(const unsigned*)&code[t0];
        cwB = *(const unsigned*)&code[t0 + 4];
    } else if (t0 < Eh) {
        if (t0+0<Eh){s0=ei[t0+0];d0=ei[(size_t)E+t0+0];cwA|=(unsigned)code[t0+0];}
        if (t0+1<Eh){s1=ei[t0+1];d1=ei[(size_t)E+t0+1];cwA|=(unsigned)code[t0+1]<<8;}
        if (t0+2<Eh){s2=ei[t0+2];d2=ei[(size_t)E+t0+2];cwA|=(unsigned)code[t0+2]<<16;}
        if (t0+3<Eh){s3=ei[t0+3];d3=ei[(size_t)E+t0+3];cwA|=(unsigned)code[t0+3]<<24;}
        if (t0+4<Eh){s4=ei[t0+4];d4=ei[(size_t)E+t0+4];cwB|=(unsigned)code[t0+4];}
        if (t0+5<Eh){s5=ei[t0+5];d5=ei[(size_t)E+t0+5];cwB|=(unsigned)code[t0+5]<<8;}
        if (t0+6<Eh){s6=ei[t0+6];d6=ei[(size_t)E+t0+6];cwB|=(unsigned)code[t0+6]<<16;}
    }
    bool w0=(t0+0<Eh),w1=(t0+1<Eh),w2=(t0+2<Eh),w3=(t0+3<Eh);
    bool w4=(t0+4<Eh),w5=(t0+5<Eh),w6=(t0+6<Eh),w7=(t0+7<Eh);
    unsigned char rs0=rnd2[s0],rs1=rnd2[s1],rs2=rnd2[s2],rs3=rnd2[s3];
    unsigned char rs4=rnd2[s4],rs5=rnd2[s5],rs6=rnd2[s6],rs7=rnd2[s7];
    unsigned char rd0=rnd2[d0],rd1=rnd2[d1],rd2=rnd2[d2],rd3=rnd2[d3];
    unsigned char rd4=rnd2[d4],rd5=rnd2[d5],rd6=rnd2[d6],rd7=rnd2[d7];
    bool ka0=false,ka1=false,ka2=false,ka3=false,ka4=false,ka5=false,ka6=false,ka7=false;
    bool kb0=false,kb1=false,kb2=false,kb3=false,kb4=false,kb5=false,kb6=false,kb7=false;
    int cnt = 0;
#define SWEEP1(CW, J, VV, SS, DD, RS, RD, KA, KB)                             \
    if (VV) {                                                                 \
        unsigned cd = (CW >> (8 * J)) & 0xFFu;                                \
        if (cd & 1u) {                                                        \
            if (RS == 1) {                                                    \
                if (RD >= 2) {                                                \
                    int old = atomicMin(&best[DD], bsnap[SS] + (1 << RSHIFT));\
                    if (old == SENT32) rnd[DD] = 2;                           \
                }                                                             \
            } else if (RS != 0 && RD == 0xFF) { KA = true; ++cnt; }           \
        }                                                                     \
        if (cd & 2u) {                                                        \
            if (RD == 1) {                                                    \
                if (RS >= 2) {                                                \
                    int old = atomicMin(&best[SS], bsnap[DD] + (1 << RSHIFT));\
                    if (old == SENT32) rnd[SS] = 2;                           \
                }                                                             \
            } else if (RD != 0 && RS == 0xFF) { KB = true; ++cnt; }           \
        }                                                                     \
    }
    SWEEP1(cwA, 0, w0, s0, d0, rs0, rd0, ka0, kb0)
    SWEEP1(cwA, 1, w1, s1, d1, rs1, rd1, ka1, kb1)
    SWEEP1(cwA, 2, w2, s2, d2, rs2, rd2, ka2, kb2)
    SWEEP1(cwA, 3, w3, s3, d3, rs3, rd3, ka3, kb3)
    SWEEP1(cwB, 0, w4, s4, d4, rs4, rd4, ka4, kb4)
    SWEEP1(cwB, 1, w5, s5, d5, rs5, rd5, ka5, kb5)
    SWEEP1(cwB, 2, w6, s6, d6, rs6, rd6, ka6, kb6)
    SWEEP1(cwB, 3, w7, s7, d7, rs7, rd7, ka7, kb7)
#undef SWEEP1
    int base = block_alloc(cnt, &dcnt[2], lds);
    if (ka0) dst[base++] = make_int2(s0, d0);
    if (kb0) dst[base++] = make_int2(d0, s0);
    if (ka1) dst[base++] = make_int2(s1, d1);
    if (kb1) dst[base++] = make_int2(d1, s1);
    if (ka2) dst[base++] = make_int2(s2, d2);
    if (kb2) dst[base++] = make_int2(d2, s2);
    if (ka3) dst[base++] = make_int2(s3, d3);
    if (kb3) dst[base++] = make_int2(d3, s3);
    if (ka4) dst[base++] = make_int2(s4, d4);
    if (kb4) dst[base++] = make_int2(d4, s4);
    if (ka5) dst[base++] = make_int2(s5, d5);
    if (kb5) dst[base++] = make_int2(d5, s5);
    if (ka6) dst[base++] = make_int2(s6, d6);
    if (kb6) dst[base++] = make_int2(d6, s6);
    if (ka7) dst[base++] = make_int2(s7, d7);
    if (kb7) dst[base]   = make_int2(d7, s7);
}

// ---- 5c. one BFS level (L>=3): 4 edges/thread over shrinking list ----
__global__ __launch_bounds__(256) void k_level_e(int2* __restrict__ d0p,
                                                 int2* __restrict__ d1p,
                                                 int* __restrict__ dcnt,
                                                 int* __restrict__ best,
                                                 unsigned char* __restrict__ rnd,
                                                 int L) {
    int ne = dcnt[L - 1];
    if (ne == 0) return;
    const int2* src = ((L - 1) & 1) ? d1p : d0p;
    int2* dst = (L & 1) ? d1p : d0p;
    __shared__ int lds[8];
    const unsigned char Lf = (unsigned char)(L - 1), Lc = (unsigned char)L;
    int stride = gridDim.x * 1024;
    for (int base = blockIdx.x * 1024; base < ne; base += stride) {
        int i0 = base + threadIdx.x * 4;
        int2 e0 = make_int2(0, 0), e1 = e0, e2 = e0, e3 = e0;
        bool v0 = (i0 < ne), v1 = (i0 + 1 < ne), v2 = (i0 + 2 < ne), v3 = (i0 + 3 < ne);
        if (v3) {
            int4 a = *(const int4*)&src[i0];
            int4 b2 = *(const int4*)&src[i0 + 2];
            e0 = make_int2(a.x, a.y);   e1 = make_int2(a.z, a.w);
            e2 = make_int2(b2.x, b2.y); e3 = make_int2(b2.z, b2.w);
        } else {
            if (v0) e0 = src[i0];
            if (v1) e1 = src[i0 + 1];
            if (v2) e2 = src[i0 + 2];
        }
        unsigned char rs0 = rnd[e0.x], rs1 = rnd[e1.x], rs2 = rnd[e2.x], rs3 = rnd[e3.x];
        unsigned char rd0 = rnd[e0.y], rd1 = rnd[e1.y], rd2 = rnd[e2.y], rd3 = rnd[e3.y];
        bool k0 = false, k1 = false, k2 = false, k3 = false;
        int cnt = 0;
#define LEVEL1(VV, EE, RS, RD, KK)                                            \
    if (VV) {                                                                 \
        if (RS == Lf) {                                                       \
            if (RD >= Lc) {                                                   \
                int old = atomicMin(&best[EE.y], best[EE.x] + (1 << RSHIFT)); \
                if (old == SENT32) rnd[EE.y] = Lc;                            \
            }                                                                 \
        } else if (RD == 0xFF) { KK = true; ++cnt; }                          \
    }
        LEVEL1(v0, e0, rs0, rd0, k0)
        LEVEL1(v1, e1, rs1, rd1, k1)
        LEVEL1(v2, e2, rs2, rd2, k2)
        LEVEL1(v3, e3, rs3, rd3, k3)
#undef LEVEL1
        int wbase = block_alloc(cnt, &dcnt[L], lds);
        if (k0) dst[wbase++] = e0;
        if (k1) dst[wbase++] = e1;
        if (k2) dst[wbase++] = e2;
        if (k3) dst[wbase]   = e3;
        __syncthreads();
    }
}

// ---- 5d. safety net: levels beyond NLEVELS, single block ----
__global__ __launch_bounds__(1024) void k_tail_e(int2* __restrict__ d0p,
                                                 int2* __restrict__ d1p,
                                                 int* __restrict__ dcnt,
                                                 int* __restrict__ best) {
    for (int L = NLEVELS + 1; L < 2000; ++L) {
        int ne = dcnt[L - 1];
        if (ne == 0) return;
        const int2* src = ((L - 1) & 1) ? d1p : d0p;
        int2* dst = (L & 1) ? d1p : d0p;
        for (int i = threadIdx.x; i < ne; i += blockDim.x) {
            int2 ed = src[i];
            int bs = best[ed.x];
            if ((bs >> RSHIFT) == L - 1) {
                int cand = bs + (1 << RSHIFT);
                if (best[ed.y] > cand) atomicMin(&best[ed.y], cand);
            } else if (best[ed.y] == SENT32) {
                int pos = atomicAdd(&dcnt[L], 1);
                dst[pos] = ed;
            }
        }
        __threadfence();
        __syncthreads();
    }
}

// ---- 6. seg labels + cluster_batch + softmax weight + 8-shadow hist ----
__global__ __launch_bounds__(256) void k_segw2(const int* __restrict__ best,
                                               const int* __restrict__ new_id,
                                               const float* __restrict__ elev32,
                                               const int* __restrict__ batch,
                                               int* __restrict__ seg,
                                               float* __restrict__ out_seg,
                                               float* __restrict__ out_cb,
                                               float* __restrict__ wbuf,
                                               int* __restrict__ hist8, int N) {
    int n = blockIdx.x * 256 + threadIdx.x;
    if (n >= N) return;
    int a = best[n];
    int sg = 0;
    float wv = 0.0f;
    if (a != SENT32) {
        int pk = a & IDMASK;
        sg = new_id[pk];
        if ((a >> RSHIFT) == 0) out_cb[sg] = (float)batch[n];
        wv = expf(elev32[n] - elev32[pk]);
    }
    seg[n] = sg;
    out_seg[n] = (float)sg;
    wbuf[n] = wv;
    atomicAdd(&hist8[(size_t)(blockIdx.x & 7) * N + sg], 1);
}

// ---- 6a. hist scan: per-block partials of summed hist8 ----
__global__ __launch_bounds__(256) void k_scan_part_h(const int* __restrict__ hist8,
                                                     int* __restrict__ part, int N) {
    int n = blockIdx.x * 256 + threadIdx.x;
    int f = 0;
    if (n < N)
        for (int k = 0; k < 8; ++k) f += hist8[(size_t)k * N + n];
#pragma unroll
    for (int off = 32; off > 0; off >>= 1) f += __shfl_down(f, off, 64);
    __shared__ int ws[4];
    int lane = threadIdx.x & 63, wid = threadIdx.x >> 6;
    if (lane == 0) ws[wid] = f;
    __syncthreads();
    if (threadIdx.x == 0) part[blockIdx.x] = ws[0] + ws[1] + ws[2] + ws[3];
}

// ---- 6b. hist scan final: cstart (exclusive) + 8 shadow cursors ----
__global__ __launch_bounds__(256) void k_scan_final_h(const int* __restrict__ hist8,
                                                      const int* __restrict__ offs,
                                                      int* __restrict__ cstart,
                                                      int* __restrict__ cursor8, int N) {
    __shared__ int tmp[256];
    int n = blockIdx.x * 256 + threadIdx.x;
    int h0=0,h1=0,h2=0,h3=0,h4=0,h5=0,h6=0,h7=0;
    if (n < N) {
        h0 = hist8[(size_t)0 * N + n]; h1 = hist8[(size_t)1 * N + n];
        h2 = hist8[(size_t)2 * N + n]; h3 = hist8[(size_t)3 * N + n];
        h4 = hist8[(size_t)4 * N + n]; h5 = hist8[(size_t)5 * N + n];
        h6 = hist8[(size_t)6 * N + n]; h7 = hist8[(size_t)7 * N + n];
    }
    int f = h0 + h1 + h2 + h3 + h4 + h5 + h6 + h7;
    tmp[threadIdx.x] = f;
    __syncthreads();
    for (int off = 1; off < 256; off <<= 1) {
        int t = (threadIdx.x >= off) ? tmp[threadIdx.x - off] : 0;
        __syncthreads();
        tmp[threadIdx.x] += t;
        __syncthreads();
    }
    if (n < N) {
        int run = offs[blockIdx.x] + tmp[threadIdx.x] - f;  // exclusive
        cstart[n] = run;
        cursor8[(size_t)0 * N + n] = run; run += h0;
        cursor8[(size_t)1 * N + n] = run; run += h1;
        cursor8[(size_t)2 * N + n] = run; run += h2;
        cursor8[(size_t)3 * N + n] = run; run += h3;
        cursor8[(size_t)4 * N + n] = run; run += h4;
        cursor8[(size_t)5 * N + n] = run; run += h5;
        cursor8[(size_t)6 * N + n] = run; run += h6;
        cursor8[(size_t)7 * N + n] = run;
    }
}

// ---- 6c. member fill via shadow cursors ----
__global__ __launch_bounds__(256) void k_cfill2(const int* __restrict__ seg,
                                                int* __restrict__ cursor8,
                                                int* __restrict__ members, int N) {
    int n = blockIdx.x * 256 + threadIdx.x;
    if (n >= N) return;
    int sg = seg[n];
    int pos = atomicAdd(&cursor8[(size_t)(blockIdx.x & 7) * N + sg], 1);
    members[pos] = n;
}

// ---- 6d. z[cl] via wave-per-cluster shuffle reduce, plain store ----
__global__ __launch_bounds__(256) void k_zsum(const int* __restrict__ members,
                                              const int* __restrict__ cstart,
                                              const float* __restrict__ wbuf,
                                              const int* __restrict__ Kptr,
                                              float* __restrict__ z, int N) {
    int lane = threadIdx.x & 63;
    int w = blockIdx.x * (blockDim.x >> 6) + (threadIdx.x >> 6);
    int nw = gridDim.x * (blockDim.x >> 6);
    int K = Kptr[0];
    for (int cl = w; cl < K; cl += nw) {
        int s0 = cstart[cl];
        int s1 = (cl + 1 < N) ? cstart[cl + 1] : N;
        float sum = 0.0f;
        for (int i = s0 + lane; i < s1; i += 64) sum += wbuf[members[i]];
#pragma unroll
        for (int off = 32; off > 0; off >>= 1) sum += __shfl_down(sum, off, 64);
        if (lane == 0) z[cl] = sum;
    }
}

// ---- 7. pooling: wave-per-POOLM-chunk, lane-parallel prefetch ----
__global__ __launch_bounds__(256) void k_pool_seg(const float* __restrict__ x,
                                                  const int* __restrict__ members,
                                                  const int* __restrict__ seg,
                                                  const float* __restrict__ wbuf,
                                                  const float* __restrict__ z,
                                                  float* __restrict__ out_scaling,
                                                  float* __restrict__ out_pooled,
                                                  int N, int C) {
    int lane = threadIdx.x & 63;
    int w = blockIdx.x * (blockDim.x >> 6) + (threadIdx.x >> 6);
    int i0 = w * POOLM;
    if (i0 >= N) return;
    int cntN = min(POOLM, N - i0);
    int mm = 0, sgv = 0;
    float wv0 = 0.0f, zz0 = 1.0f;
    if (lane < cntN) mm = members[i0 + lane];
    if (lane < cntN) { sgv = seg[mm]; wv0 = wbuf[mm]; }
    if (lane < cntN) zz0 = z[sgv] + 1e-12f;
    int c1 = lane + 64;
    bool has1 = (c1 < C);
    float a0 = 0.0f, a1 = 0.0f;
    int cur = -1;
    for (int j = 0; j < cntN; ++j) {
        int node = __shfl(mm, j, 64);
        int sg = __shfl(sgv, j, 64);
        float sc = __shfl(wv0, j, 64) / __shfl(zz0, j, 64);
        if (sg != cur) {
            if (cur >= 0) {
                float* pr = out_pooled + (size_t)cur * C;
                atomicAdd(&pr[lane], a0);
                if (has1) atomicAdd(&pr[c1], a1);
            }
            cur = sg;
            a0 = a1 = 0.0f;
        }
        if (lane == 0) out_scaling[node] = sc;
        const float* xr = x + (size_t)node * C;
        a0 += xr[lane] * sc;
        if (has1) a1 += xr[c1] * sc;
    }
    float* pr = out_pooled + (size_t)cur * C;
    atomicAdd(&pr[lane], a0);
    if (has1) atomicAdd(&pr[c1], a1);
}

extern "C" void kernel_launch(void* const* d_in, const int* in_sizes, int n_in,
                              void* d_out, int out_size, void* d_ws, size_t ws_size,
                              hipStream_t stream) {
    const float* x = (const float*)d_in[0];
    const float* W = (const float*)d_in[1];
    const float* b = (const float*)d_in[2];
    const int* ei = (const int*)d_in[3];
    const int* batch = (const int*)d_in[4];

    const int C = in_sizes[1];           // 128
    const int N = in_sizes[0] / C;       // 100000
    const int E = in_sizes[3] / 2;       // 3200000
    const int Eh = E / 2;                // 1600000 undirected pairs

    float* out_pooled   = (float*)d_out;
    float* out_seg      = out_pooled + (size_t)N * C;
    float* out_scaling  = out_seg + N;
    float* out_cb       = out_scaling + N;
    float* out_ispeak   = out_cb + N;
    float* out_istrough = out_ispeak + N;

    char* p = (char*)d_ws;
    auto alloc = [&](size_t bytes) -> char* {
        char* r = p;
        p += (bytes + 255) & ~(size_t)255;
        return r;
    };
    double* elev64 = (double*)alloc((size_t)N * 8);
    float* elev32  = (float*)alloc((size_t)N * 4);
    int* best      = (int*)alloc((size_t)N * 4);
    int* bsnap     = (int*)alloc((size_t)N * 4);
    int* peakflag  = (int*)alloc((size_t)N * 4);
    int* new_id    = (int*)alloc((size_t)N * 4);
    int* seg       = (int*)alloc((size_t)N * 4);
    float* wbuf    = (float*)alloc((size_t)N * 4);
    int* members   = (int*)alloc((size_t)N * 4);
    int* cstart    = (int*)alloc((size_t)N * 4);
    int* cursor8   = (int*)alloc((size_t)N * 4 * 8);
    float* z       = (float*)alloc((size_t)N * 4);
    unsigned char* rnd  = (unsigned char*)alloc((size_t)N);
    unsigned char* rnd2 = (unsigned char*)alloc((size_t)N);
    const int P = (N + 255) / 256;
    int* part = (int*)alloc((size_t)P * 4);
    int* offs = (int*)alloc((size_t)P * 4);
    unsigned char* code = (unsigned char*)alloc((size_t)Eh);
    char* zbeg = p;  // zero-initialized region starts here
    unsigned char* notpeak   = (unsigned char*)alloc((size_t)N);
    unsigned char* nottrough = (unsigned char*)alloc((size_t)N);
    int* hist8 = (int*)alloc((size_t)N * 4 * 8);
    int* dcnt  = (int*)alloc(2048 * 4);
    size_t zspan = (size_t)(p - zbeg);
    int2* down0 = (int2*)alloc((size_t)E * 8);
    int2* down1 = (int2*)alloc((size_t)E * 8);
    int* Kptr = dcnt + 1024;
    (void)ws_size;

    hipMemsetAsync(zbeg, 0, zspan, stream);
    hipMemsetAsync(out_pooled, 0, (size_t)N * C * sizeof(float), stream);

    const int B4 = (Eh + 1023) / 1024;   // 4 pairs per thread
    const int B8 = (Eh + 2047) / 2048;   // 8 pairs per thread

    k_matvec<<<(N + 3) / 4, 256, 0, stream>>>(x, W, b, elev64, elev32, N, C);
    k_mark<<<B4, 256, 0, stream>>>(ei, elev64, elev32, notpeak, nottrough,
                                   code, Eh, E);
    k_nodes1<<<P, 256, 0, stream>>>(notpeak, nottrough, peakflag, best, rnd,
                                    out_ispeak, out_istrough, out_cb, part, N);
    k_scan_offs<<<1, 64, 0, stream>>>(part, offs, P);

    k_build_l1<<<B8, 256, 0, stream>>>(ei, code, notpeak, best, rnd, Eh, E);
    k_scan_final0<<<P, 256, 0, stream>>>(peakflag, offs, best, rnd, new_id,
                                         bsnap, rnd2, Kptr, N);
    k_sweep2<<<B8, 256, 0, stream>>>(ei, code, bsnap, rnd2, best, rnd,
                                     down0, dcnt, Eh, E);

    for (int L = 3; L <= NLEVELS; ++L)
        k_level_e<<<2048, 256, 0, stream>>>(down0, down1, dcnt, best, rnd, L);
    k_tail_e<<<1, 1024, 0, stream>>>(down0, down1, dcnt, best);

    k_segw2<<<P, 256, 0, stream>>>(best, new_id, elev32, batch, seg, out_seg,
                                   out_cb, wbuf, hist8, N);
    k_scan_part_h<<<P, 256, 0, stream>>>(hist8, part, N);
    k_scan_offs<<<1, 64, 0, stream>>>(part, offs, P);
    k_scan_final_h<<<P, 256, 0, stream>>>(hist8, offs, cstart, cursor8, N);
    k_cfill2<<<P, 256, 0, stream>>>(seg, cursor8, members, N);
    k_zsum<<<128, 256, 0, stream>>>(members, cstart, wbuf, Kptr, z, N);

    const int NW = (N + POOLM - 1) / POOLM;
    k_pool_seg<<<(NW + 3) / 4, 256, 0, stream>>>(x, members, seg, wbuf, z,
                                                 out_scaling, out_pooled, N, C);
}

// Round 20
// 201.871 us; speedup vs baseline: 1.0217x; 1.0217x over previous
//
#include <hip/hip_runtime.h>

#define SENT32 0x7FFFFFFF
#define IDMASK 0x1FFFF
#define RSHIFT 17
#define NLEVELS 5
#define POOLM 16

// block-wide allocation: per-thread cnt -> contiguous base in *gctr.
__device__ __forceinline__ int block_alloc(int cnt, int* gctr, int* lds) {
    int lane = threadIdx.x & 63, wid = threadIdx.x >> 6;
    int pfx = cnt;
#pragma unroll
    for (int off = 1; off < 64; off <<= 1) {
        int t = __shfl_up(pfx, off, 64);
        if (lane >= off) pfx += t;
    }
    if (lane == 63) lds[wid] = pfx;
    __syncthreads();
    if (threadIdx.x == 0) {
        int t = lds[0] + lds[1] + lds[2] + lds[3];
        int bse = t ? atomicAdd(gctr, t) : 0;
        lds[4] = bse;
        lds[5] = bse + lds[0];
        lds[6] = lds[5] + lds[1];
        lds[7] = lds[6] + lds[2];
    }
    __syncthreads();
    return lds[4 + wid] + pfx - cnt;
}

// ---- 0. fast zero-fill: float4 grid-stride over two regions ----
__global__ __launch_bounds__(256) void k_zero(float4* __restrict__ a, size_t na,
                                              float4* __restrict__ bz, size_t nb) {
    size_t i = (size_t)blockIdx.x * 256 + threadIdx.x;
    size_t stride = (size_t)gridDim.x * 256;
    float4 zv = make_float4(0.f, 0.f, 0.f, 0.f);
    for (size_t j = i; j < na; j += stride) a[j] = zv;
    for (size_t j = i; j < nb; j += stride) bz[j] = zv;
}

// ---- 1. elevation: elev = x @ W + b, f64 accumulation, wave-per-row ----
__global__ __launch_bounds__(256) void k_matvec(const float* __restrict__ x,
                                                const float* __restrict__ W,
                                                const float* __restrict__ b,
                                                double* __restrict__ elev64,
                                                float* __restrict__ elev32,
                                                int N, int C) {
    int lane = threadIdx.x & 63;
    int wib  = threadIdx.x >> 6;
    int row  = blockIdx.x * (blockDim.x >> 6) + wib;
    if (row >= N) return;
    const float* xr = x + (size_t)row * C;
    double s = 0.0;
    for (int c = lane; c < C; c += 64) s += (double)xr[c] * (double)W[c];
#pragma unroll
    for (int off = 32; off > 0; off >>= 1) s += __shfl_down(s, off, 64);
    if (lane == 0) {
        double v = s + (double)b[0];
        elev64[row] = v;
        elev32[row] = (float)v;
    }
}

// ---- 2. mark pass, 4 pairs/thread. f32 compare with f64 fallback on ties ----
__global__ __launch_bounds__(256) void k_mark(const int* __restrict__ ei,
                                              const double* __restrict__ elev64,
                                              const float* __restrict__ elev32,
                                              unsigned char* __restrict__ notpeak,
                                              unsigned char* __restrict__ nottrough,
                                              unsigned char* __restrict__ code,
                                              int Eh, int E) {
    int t0 = (blockIdx.x * 256 + threadIdx.x) * 4;
    if (t0 >= Eh) return;
    bool v0 = true, v1 = (t0 + 1 < Eh), v2 = (t0 + 2 < Eh), v3 = (t0 + 3 < Eh);
    int s0 = 0, s1 = 0, s2 = 0, s3 = 0, d0 = 0, d1 = 0, d2 = 0, d3 = 0;
    if (v3) {
        int4 sv = *(const int4*)&ei[t0];
        int4 dv = *(const int4*)&ei[(size_t)E + t0];
        s0 = sv.x; s1 = sv.y; s2 = sv.z; s3 = sv.w;
        d0 = dv.x; d1 = dv.y; d2 = dv.z; d3 = dv.w;
    } else {
        s0 = ei[t0];            d0 = ei[(size_t)E + t0];
        if (v1) { s1 = ei[t0 + 1]; d1 = ei[(size_t)E + t0 + 1]; }
        if (v2) { s2 = ei[t0 + 2]; d2 = ei[(size_t)E + t0 + 2]; }
    }
    float fs0 = elev32[s0], fs1 = elev32[s1], fs2 = elev32[s2], fs3 = elev32[s3];
    float fd0 = elev32[d0], fd1 = elev32[d1], fd2 = elev32[d2], fd3 = elev32[d3];
    unsigned cw = 0;
#define MARK1(J, VV, SS, DD, FS, FD)                                          \
    if (VV) {                                                                 \
        unsigned c;                                                           \
        if (FD < FS)      { notpeak[DD] = 1; nottrough[SS] = 1; c = 1u; }     \
        else if (FD > FS) { notpeak[SS] = 1; nottrough[DD] = 1; c = 2u; }     \
        else {                                                                \
            double ax = elev64[SS], bx = elev64[DD];                          \
            if (bx < ax)      { notpeak[DD] = 1; nottrough[SS] = 1; c = 1u; } \
            else if (bx > ax) { notpeak[SS] = 1; nottrough[DD] = 1; c = 2u; } \
            else c = 3u;                                                      \
        }                                                                     \
        cw |= c << (8 * J);                                                   \
    }
    MARK1(0, v0, s0, d0, fs0, fd0)
    MARK1(1, v1, s1, d1, fs1, fd1)
    MARK1(2, v2, s2, d2, fs2, fd2)
    MARK1(3, v3, s3, d3, fs3, fd3)
#undef MARK1
    if (v3) {
        *(unsigned*)&code[t0] = cw;
    } else {
        code[t0] = (unsigned char)(cw & 0xFF);
        if (v1) code[t0 + 1] = (unsigned char)((cw >> 8) & 0xFF);
        if (v2) code[t0 + 2] = (unsigned char)((cw >> 16) & 0xFF);
    }
}

// ---- 3. node pass: flags, best/rnd init, per-block peak partials ----
__global__ __launch_bounds__(256) void k_nodes1(const unsigned char* __restrict__ notpeak,
                                                const unsigned char* __restrict__ nottrough,
                                                int* __restrict__ peakflag,
                                                int* __restrict__ best,
                                                unsigned char* __restrict__ rnd,
                                                float* __restrict__ out_ispeak,
                                                float* __restrict__ out_istrough,
                                                float* __restrict__ out_cb,
                                                int* __restrict__ part, int N) {
    __shared__ int ws[4];
    int n = blockIdx.x * 256 + threadIdx.x;
    int lane = threadIdx.x & 63, wid = threadIdx.x >> 6;
    int pk = 0;
    if (n < N) {
        pk = notpeak[n] ? 0 : 1;
        int tr = nottrough[n] ? 0 : 1;
        peakflag[n] = pk;
        out_ispeak[n] = (float)pk;
        out_istrough[n] = (float)tr;
        best[n] = pk ? n : SENT32;
        rnd[n] = pk ? 0 : 0xFF;
        out_cb[n] = -1.0f;
    }
    unsigned long long mk = __ballot(pk);
    if (lane == 0) ws[wid] = __popcll(mk);
    __syncthreads();
    if (threadIdx.x == 0) part[blockIdx.x] = ws[0] + ws[1] + ws[2] + ws[3];
}

// ---- 4. scan helpers ----
__global__ __launch_bounds__(64) void k_scan_offs(const int* __restrict__ part,
                                                  int* __restrict__ offs, int P) {
    int lane = threadIdx.x;
    int chunk = (P + 63) / 64;
    int s0 = lane * chunk, s1 = min(s0 + chunk, P);
    int s = 0;
    for (int j = s0; j < s1; ++j) s += part[j];
    int incl = s;
#pragma unroll
    for (int off = 1; off < 64; off <<= 1) {
        int t = __shfl_up(incl, off, 64);
        if (lane >= off) incl += t;
    }
    int run = incl - s;
    for (int j = s0; j < s1; ++j) { offs[j] = run; run += part[j]; }
}

// new_id = inclusive_scan(peakflag)-1; fused: bsnap + rnd2 snapshot + K
__global__ __launch_bounds__(256) void k_scan_final0(const int* __restrict__ flag,
                                                     const int* __restrict__ offs,
                                                     const int* __restrict__ best,
                                                     const unsigned char* __restrict__ rnd,
                                                     int* __restrict__ new_id,
                                                     int* __restrict__ bsnap,
                                                     unsigned char* __restrict__ rnd2,
                                                     int* __restrict__ Kptr, int N) {
    __shared__ int tmp[256];
    int n = blockIdx.x * 256 + threadIdx.x;
    int f = (n < N) ? flag[n] : 0;
    tmp[threadIdx.x] = f;
    __syncthreads();
    for (int off = 1; off < 256; off <<= 1) {
        int t = (threadIdx.x >= off) ? tmp[threadIdx.x - off] : 0;
        __syncthreads();
        tmp[threadIdx.x] += t;
        __syncthreads();
    }
    if (n < N) {
        int incl = offs[blockIdx.x] + tmp[threadIdx.x];
        new_id[n] = incl - 1;
        bsnap[n] = best[n];
        rnd2[n] = rnd[n];
        if (n == N - 1) Kptr[0] = incl;
    }
}

// ---- 5a. BFS level 1: streaming relax, 8 pairs/thread ----
__global__ __launch_bounds__(256) void k_build_l1(const int* __restrict__ ei,
                                                  const unsigned char* __restrict__ code,
                                                  const unsigned char* __restrict__ notpeak,
                                                  int* __restrict__ best,
                                                  unsigned char* __restrict__ rnd,
                                                  int Eh, int E) {
    int t0 = (blockIdx.x * 256 + threadIdx.x) * 8;
    if (t0 >= Eh) return;
    int s0=0,s1=0,s2=0,s3=0,s4=0,s5=0,s6=0,s7=0;
    int d0=0,d1=0,d2=0,d3=0,d4=0,d5=0,d6=0,d7=0;
    unsigned cwA = 0, cwB = 0;
    if (t0 + 8 <= Eh) {
        int4 sa = *(const int4*)&ei[t0];
        int4 sb = *(const int4*)&ei[t0 + 4];
        int4 da = *(const int4*)&ei[(size_t)E + t0];
        int4 db = *(const int4*)&ei[(size_t)E + t0 + 4];
        s0=sa.x;s1=sa.y;s2=sa.z;s3=sa.w; s4=sb.x;s5=sb.y;s6=sb.z;s7=sb.w;
        d0=da.x;d1=da.y;d2=da.z;d3=da.w; d4=db.x;d5=db.y;d6=db.z;d7=db.w;
        cwA = *(const unsigned*)&code[t0];
        cwB = *(const unsigned*)&code[t0 + 4];
    } else {
        if (t0+0<Eh){s0=ei[t0+0];d0=ei[(size_t)E+t0+0];cwA|=(unsigned)code[t0+0];}
        if (t0+1<Eh){s1=ei[t0+1];d1=ei[(size_t)E+t0+1];cwA|=(unsigned)code[t0+1]<<8;}
        if (t0+2<Eh){s2=ei[t0+2];d2=ei[(size_t)E+t0+2];cwA|=(unsigned)code[t0+2]<<16;}
        if (t0+3<Eh){s3=ei[t0+3];d3=ei[(size_t)E+t0+3];cwA|=(unsigned)code[t0+3]<<24;}
        if (t0+4<Eh){s4=ei[t0+4];d4=ei[(size_t)E+t0+4];cwB|=(unsigned)code[t0+4];}
        if (t0+5<Eh){s5=ei[t0+5];d5=ei[(size_t)E+t0+5];cwB|=(unsigned)code[t0+5]<<8;}
        if (t0+6<Eh){s6=ei[t0+6];d6=ei[(size_t)E+t0+6];cwB|=(unsigned)code[t0+6]<<16;}
    }
    bool w0=(t0+0<Eh),w1=(t0+1<Eh),w2=(t0+2<Eh),w3=(t0+3<Eh);
    bool w4=(t0+4<Eh),w5=(t0+5<Eh),w6=(t0+6<Eh),w7=(t0+7<Eh);
    unsigned char nps0=notpeak[s0],nps1=notpeak[s1],nps2=notpeak[s2],nps3=notpeak[s3];
    unsigned char nps4=notpeak[s4],nps5=notpeak[s5],nps6=notpeak[s6],nps7=notpeak[s7];
    unsigned char npd0=notpeak[d0],npd1=notpeak[d1],npd2=notpeak[d2],npd3=notpeak[d3];
    unsigned char npd4=notpeak[d4],npd5=notpeak[d5],npd6=notpeak[d6],npd7=notpeak[d7];
#define BUILD1(CW, J, VV, SS, DD, NPS, NPD)                                   \
    if (VV) {                                                                 \
        unsigned cd = (CW >> (8 * J)) & 0xFFu;                                \
        bool ps = !NPS, pd = !NPD;                                            \
        if ((cd & 1u) && ps && !pd) {                                         \
            int old = atomicMin(&best[DD], (1 << RSHIFT) | SS);               \
            if (old == SENT32) rnd[DD] = 1;                                   \
        }                                                                     \
        if ((cd & 2u) && pd && !ps) {                                         \
            int old = atomicMin(&best[SS], (1 << RSHIFT) | DD);               \
            if (old == SENT32) rnd[SS] = 1;                                   \
        }                                                                     \
    }
    BUILD1(cwA, 0, w0, s0, d0, nps0, npd0)
    BUILD1(cwA, 1, w1, s1, d1, nps1, npd1)
    BUILD1(cwA, 2, w2, s2, d2, nps2, npd2)
    BUILD1(cwA, 3, w3, s3, d3, nps3, npd3)
    BUILD1(cwB, 0, w4, s4, d4, nps4, npd4)
    BUILD1(cwB, 1, w5, s5, d5, nps5, npd5)
    BUILD1(cwB, 2, w6, s6, d6, nps6, npd6)
    BUILD1(cwB, 3, w7, s7, d7, nps7, npd7)
#undef BUILD1
}

// ---- 5b. BFS level 2: re-stream ei/code; READ rnd2 snapshot, WRITE rnd ----
__global__ __launch_bounds__(256) void k_sweep2(const int* __restrict__ ei,
                                                const unsigned char* __restrict__ code,
                                                const int* __restrict__ bsnap,
                                                const unsigned char* __restrict__ rnd2,
                                                int* __restrict__ best,
                                                unsigned char* __restrict__ rnd,
                                                int2* __restrict__ dst,
                                                int* __restrict__ dcnt,
                                                int Eh, int E) {
    __shared__ int lds[8];
    int t0 = (blockIdx.x * 256 + threadIdx.x) * 8;
    int s0=0,s1=0,s2=0,s3=0,s4=0,s5=0,s6=0,s7=0;
    int d0=0,d1=0,d2=0,d3=0,d4=0,d5=0,d6=0,d7=0;
    unsigned cwA = 0, cwB = 0;
    if (t0 + 8 <= Eh) {
        int4 sa = *(const int4*)&ei[t0];
        int4 sb = *(const int4*)&ei[t0 + 4];
        int4 da = *(const int4*)&ei[(size_t)E + t0];
        int4 db = *(const int4*)&ei[(size_t)E + t0 + 4];
        s0=sa.x;s1=sa.y;s2=sa.z;s3=sa.w; s4=sb.x;s5=sb.y;s6=sb.z;s7=sb.w;
        d0=da.x;d1=da.y;d2=da.z;d3=da.w; d4=db.x;d5=db.y;d6=db.z;d7=db.w;
        cwA = *(const unsigned*)&code[t0];
        cwB = *(const unsigned*)&code[t0 + 4];
    } else if (t0 < Eh) {
        if (t0+0<Eh){s0=ei[t0+0];d0=ei[(size_t)E+t0+0];cwA|=(unsigned)code[t0+0];}
        if (t0+1<Eh){s1=ei[t0+1];d1=ei[(size_t)E+t0+1];cwA|=(unsigned)code[t0+1]<<8;}
        if (t0+2<Eh){s2=ei[t0+2];d2=ei[(size_t)E+t0+2];cwA|=(unsigned)code[t0+2]<<16;}
        if (t0+3<Eh){s3=ei[t0+3];d3=ei[(size_t)E+t0+3];cwA|=(unsigned)code[t0+3]<<24;}
        if (t0+4<Eh){s4=ei[t0+4];d4=ei[(size_t)E+t0+4];cwB|=(unsigned)code[t0+4];}
        if (t0+5<Eh){s5=ei[t0+5];d5=ei[(size_t)E+t0+5];cwB|=(unsigned)code[t0+5]<<8;}
        if (t0+6<Eh){s6=ei[t0+6];d6=ei[(size_t)E+t0+6];cwB|=(unsigned)code[t0+6]<<16;}
    }
    bool w0=(t0+0<Eh),w1=(t0+1<Eh),w2=(t0+2<Eh),w3=(t0+3<Eh);
    bool w4=(t0+4<Eh),w5=(t0+5<Eh),w6=(t0+6<Eh),w7=(t0+7<Eh);
    unsigned char rs0=rnd2[s0],rs1=rnd2[s1],rs2=rnd2[s2],rs3=rnd2[s3];
    unsigned char rs4=rnd2[s4],rs5=rnd2[s5],rs6=rnd2[s6],rs7=rnd2[s7];
    unsigned char rd0=rnd2[d0],rd1=rnd2[d1],rd2=rnd2[d2],rd3=rnd2[d3];
    unsigned char rd4=rnd2[d4],rd5=rnd2[d5],rd6=rnd2[d6],rd7=rnd2[d7];
    bool ka0=false,ka1=false,ka2=false,ka3=false,ka4=false,ka5=false,ka6=false,ka7=false;
    bool kb0=false,kb1=false,kb2=false,kb3=false,kb4=false,kb5=false,kb6=false,kb7=false;
    int cnt = 0;
#define SWEEP1(CW, J, VV, SS, DD, RS, RD, KA, KB)                             \
    if (VV) {                                                                 \
        unsigned cd = (CW >> (8 * J)) & 0xFFu;                                \
        if (cd & 1u) {                                                        \
            if (RS == 1) {                                                    \
                if (RD >= 2) {                                                \
                    int old = atomicMin(&best[DD], bsnap[SS] + (1 << RSHIFT));\
                    if (old == SENT32) rnd[DD] = 2;                           \
                }                                                             \
            } else if (RS != 0 && RD == 0xFF) { KA = true; ++cnt; }           \
        }                                                                     \
        if (cd & 2u) {                                                        \
            if (RD == 1) {                                                    \
                if (RS >= 2) {                                                \
                    int old = atomicMin(&best[SS], bsnap[DD] + (1 << RSHIFT));\
                    if (old == SENT32) rnd[SS] = 2;                           \
                }                                                             \
            } else if (RD != 0 && RS == 0xFF) { KB = true; ++cnt; }           \
        }                                                                     \
    }
    SWEEP1(cwA, 0, w0, s0, d0, rs0, rd0, ka0, kb0)
    SWEEP1(cwA, 1, w1, s1, d1, rs1, rd1, ka1, kb1)
    SWEEP1(cwA, 2, w2, s2, d2, rs2, rd2, ka2, kb2)
    SWEEP1(cwA, 3, w3, s3, d3, rs3, rd3, ka3, kb3)
    SWEEP1(cwB, 0, w4, s4, d4, rs4, rd4, ka4, kb4)
    SWEEP1(cwB, 1, w5, s5, d5, rs5, rd5, ka5, kb5)
    SWEEP1(cwB, 2, w6, s6, d6, rs6, rd6, ka6, kb6)
    SWEEP1(cwB, 3, w7, s7, d7, rs7, rd7, ka7, kb7)
#undef SWEEP1
    int base = block_alloc(cnt, &dcnt[2], lds);
    if (ka0) dst[base++] = make_int2(s0, d0);
    if (kb0) dst[base++] = make_int2(d0, s0);
    if (ka1) dst[base++] = make_int2(s1, d1);
    if (kb1) dst[base++] = make_int2(d1, s1);
    if (ka2) dst[base++] = make_int2(s2, d2);
    if (kb2) dst[base++] = make_int2(d2, s2);
    if (ka3) dst[base++] = make_int2(s3, d3);
    if (kb3) dst[base++] = make_int2(d3, s3);
    if (ka4) dst[base++] = make_int2(s4, d4);
    if (kb4) dst[base++] = make_int2(d4, s4);
    if (ka5) dst[base++] = make_int2(s5, d5);
    if (kb5) dst[base++] = make_int2(d5, s5);
    if (ka6) dst[base++] = make_int2(s6, d6);
    if (kb6) dst[base++] = make_int2(d6, s6);
    if (ka7) dst[base++] = make_int2(s7, d7);
    if (kb7) dst[base]   = make_int2(d7, s7);
}

// ---- 5c. one BFS level (L>=3): 4 edges/thread over shrinking list ----
__global__ __launch_bounds__(256) void k_level_e(int2* __restrict__ d0p,
                                                 int2* __restrict__ d1p,
                                                 int* __restrict__ dcnt,
                                                 int* __restrict__ best,
                                                 unsigned char* __restrict__ rnd,
                                                 int L) {
    int ne = dcnt[L - 1];
    if (ne == 0) return;
    const int2* src = ((L - 1) & 1) ? d1p : d0p;
    int2* dst = (L & 1) ? d1p : d0p;
    __shared__ int lds[8];
    const unsigned char Lf = (unsigned char)(L - 1), Lc = (unsigned char)L;
    int stride = gridDim.x * 1024;
    for (int base = blockIdx.x * 1024; base < ne; base += stride) {
        int i0 = base + threadIdx.x * 4;
        int2 e0 = make_int2(0, 0), e1 = e0, e2 = e0, e3 = e0;
        bool v0 = (i0 < ne), v1 = (i0 + 1 < ne), v2 = (i0 + 2 < ne), v3 = (i0 + 3 < ne);
        if (v3) {
            int4 a = *(const int4*)&src[i0];
            int4 b2 = *(const int4*)&src[i0 + 2];
            e0 = make_int2(a.x, a.y);   e1 = make_int2(a.z, a.w);
            e2 = make_int2(b2.x, b2.y); e3 = make_int2(b2.z, b2.w);
        } else {
            if (v0) e0 = src[i0];
            if (v1) e1 = src[i0 + 1];
            if (v2) e2 = src[i0 + 2];
        }
        unsigned char rs0 = rnd[e0.x], rs1 = rnd[e1.x], rs2 = rnd[e2.x], rs3 = rnd[e3.x];
        unsigned char rd0 = rnd[e0.y], rd1 = rnd[e1.y], rd2 = rnd[e2.y], rd3 = rnd[e3.y];
        bool k0 = false, k1 = false, k2 = false, k3 = false;
        int cnt = 0;
#define LEVEL1(VV, EE, RS, RD, KK)                                            \
    if (VV) {                                                                 \
        if (RS == Lf) {                                                       \
            if (RD >= Lc) {                                                   \
                int old = atomicMin(&best[EE.y], best[EE.x] + (1 << RSHIFT)); \
                if (old == SENT32) rnd[EE.y] = Lc;                            \
            }                                                                 \
        } else if (RD == 0xFF) { KK = true; ++cnt; }                          \
    }
        LEVEL1(v0, e0, rs0, rd0, k0)
        LEVEL1(v1, e1, rs1, rd1, k1)
        LEVEL1(v2, e2, rs2, rd2, k2)
        LEVEL1(v3, e3, rs3, rd3, k3)
#undef LEVEL1
        int wbase = block_alloc(cnt, &dcnt[L], lds);
        if (k0) dst[wbase++] = e0;
        if (k1) dst[wbase++] = e1;
        if (k2) dst[wbase++] = e2;
        if (k3) dst[wbase]   = e3;
        __syncthreads();
    }
}

// ---- 5d. safety net: levels beyond NLEVELS, single block ----
__global__ __launch_bounds__(1024) void k_tail_e(int2* __restrict__ d0p,
                                                 int2* __restrict__ d1p,
                                                 int* __restrict__ dcnt,
                                                 int* __restrict__ best) {
    for (int L = NLEVELS + 1; L < 2000; ++L) {
        int ne = dcnt[L - 1];
        if (ne == 0) return;
        const int2* src = ((L - 1) & 1) ? d1p : d0p;
        int2* dst = (L & 1) ? d1p : d0p;
        for (int i = threadIdx.x; i < ne; i += blockDim.x) {
            int2 ed = src[i];
            int bs = best[ed.x];
            if ((bs >> RSHIFT) == L - 1) {
                int cand = bs + (1 << RSHIFT);
                if (best[ed.y] > cand) atomicMin(&best[ed.y], cand);
            } else if (best[ed.y] == SENT32) {
                int pos = atomicAdd(&dcnt[L], 1);
                dst[pos] = ed;
            }
        }
        __threadfence();
        __syncthreads();
    }
}

// ---- 6. seg labels + cluster_batch + softmax weight + 8-shadow hist ----
__global__ __launch_bounds__(256) void k_segw2(const int* __restrict__ best,
                                               const int* __restrict__ new_id,
                                               const float* __restrict__ elev32,
                                               const int* __restrict__ batch,
                                               int* __restrict__ seg,
                                               float* __restrict__ out_seg,
                                               float* __restrict__ out_cb,
                                               float* __restrict__ wbuf,
                                               int* __restrict__ hist8, int N) {
    int n = blockIdx.x * 256 + threadIdx.x;
    if (n >= N) return;
    int a = best[n];
    int sg = 0;
    float wv = 0.0f;
    if (a != SENT32) {
        int pk = a & IDMASK;
        sg = new_id[pk];
        if ((a >> RSHIFT) == 0) out_cb[sg] = (float)batch[n];
        wv = expf(elev32[n] - elev32[pk]);
    }
    seg[n] = sg;
    out_seg[n] = (float)sg;
    wbuf[n] = wv;
    atomicAdd(&hist8[(size_t)(blockIdx.x & 7) * N + sg], 1);
}

// ---- 6a. hist scan: per-block partials of summed hist8 ----
__global__ __launch_bounds__(256) void k_scan_part_h(const int* __restrict__ hist8,
                                                     int* __restrict__ part, int N) {
    int n = blockIdx.x * 256 + threadIdx.x;
    int f = 0;
    if (n < N)
        for (int k = 0; k < 8; ++k) f += hist8[(size_t)k * N + n];
#pragma unroll
    for (int off = 32; off > 0; off >>= 1) f += __shfl_down(f, off, 64);
    __shared__ int ws[4];
    int lane = threadIdx.x & 63, wid = threadIdx.x >> 6;
    if (lane == 0) ws[wid] = f;
    __syncthreads();
    if (threadIdx.x == 0) part[blockIdx.x] = ws[0] + ws[1] + ws[2] + ws[3];
}

// ---- 6b. hist scan final: cstart (exclusive) + 8 shadow cursors ----
__global__ __launch_bounds__(256) void k_scan_final_h(const int* __restrict__ hist8,
                                                      const int* __restrict__ offs,
                                                      int* __restrict__ cstart,
                                                      int* __restrict__ cursor8, int N) {
    __shared__ int tmp[256];
    int n = blockIdx.x * 256 + threadIdx.x;
    int h0=0,h1=0,h2=0,h3=0,h4=0,h5=0,h6=0,h7=0;
    if (n < N) {
        h0 = hist8[(size_t)0 * N + n]; h1 = hist8[(size_t)1 * N + n];
        h2 = hist8[(size_t)2 * N + n]; h3 = hist8[(size_t)3 * N + n];
        h4 = hist8[(size_t)4 * N + n]; h5 = hist8[(size_t)5 * N + n];
        h6 = hist8[(size_t)6 * N + n]; h7 = hist8[(size_t)7 * N + n];
    }
    int f = h0 + h1 + h2 + h3 + h4 + h5 + h6 + h7;
    tmp[threadIdx.x] = f;
    __syncthreads();
    for (int off = 1; off < 256; off <<= 1) {
        int t = (threadIdx.x >= off) ? tmp[threadIdx.x - off] : 0;
        __syncthreads();
        tmp[threadIdx.x] += t;
        __syncthreads();
    }
    if (n < N) {
        int run = offs[blockIdx.x] + tmp[threadIdx.x] - f;  // exclusive
        cstart[n] = run;
        cursor8[(size_t)0 * N + n] = run; run += h0;
        cursor8[(size_t)1 * N + n] = run; run += h1;
        cursor8[(size_t)2 * N + n] = run; run += h2;
        cursor8[(size_t)3 * N + n] = run; run += h3;
        cursor8[(size_t)4 * N + n] = run; run += h4;
        cursor8[(size_t)5 * N + n] = run; run += h5;
        cursor8[(size_t)6 * N + n] = run; run += h6;
        cursor8[(size_t)7 * N + n] = run;
    }
}

// ---- 6c. member fill via shadow cursors ----
__global__ __launch_bounds__(256) void k_cfill2(const int* __restrict__ seg,
                                                int* __restrict__ cursor8,
                                                int* __restrict__ members, int N) {
    int n = blockIdx.x * 256 + threadIdx.x;
    if (n >= N) return;
    int sg = seg[n];
    int pos = atomicAdd(&cursor8[(size_t)(blockIdx.x & 7) * N + sg], 1);
    members[pos] = n;
}

// ---- 6d. z[cl] via wave-per-cluster shuffle reduce, plain store ----
__global__ __launch_bounds__(256) void k_zsum(const int* __restrict__ members,
                                              const int* __restrict__ cstart,
                                              const float* __restrict__ wbuf,
                                              const int* __restrict__ Kptr,
                                              float* __restrict__ z, int N) {
    int lane = threadIdx.x & 63;
    int w = blockIdx.x * (blockDim.x >> 6) + (threadIdx.x >> 6);
    int nw = gridDim.x * (blockDim.x >> 6);
    int K = Kptr[0];
    for (int cl = w; cl < K; cl += nw) {
        int s0 = cstart[cl];
        int s1 = (cl + 1 < N) ? cstart[cl + 1] : N;
        float sum = 0.0f;
        for (int i = s0 + lane; i < s1; i += 64) sum += wbuf[members[i]];
#pragma unroll
        for (int off = 32; off > 0; off >>= 1) sum += __shfl_down(sum, off, 64);
        if (lane == 0) z[cl] = sum;
    }
}

// ---- 7. pooling: wave-per-POOLM-chunk, lane-parallel prefetch ----
__global__ __launch_bounds__(256) void k_pool_seg(const float* __restrict__ x,
                                                  const int* __restrict__ members,
                                                  const int* __restrict__ seg,
                                                  const float* __restrict__ wbuf,
                                                  const float* __restrict__ z,
                                                  float* __restrict__ out_scaling,
                                                  float* __restrict__ out_pooled,
                                                  int N, int C) {
    int lane = threadIdx.x & 63;
    int w = blockIdx.x * (blockDim.x >> 6) + (threadIdx.x >> 6);
    int i0 = w * POOLM;
    if (i0 >= N) return;
    int cntN = min(POOLM, N - i0);
    int mm = 0, sgv = 0;
    float wv0 = 0.0f, zz0 = 1.0f;
    if (lane < cntN) mm = members[i0 + lane];
    if (lane < cntN) { sgv = seg[mm]; wv0 = wbuf[mm]; }
    if (lane < cntN) zz0 = z[sgv] + 1e-12f;
    int c1 = lane + 64;
    bool has1 = (c1 < C);
    float a0 = 0.0f, a1 = 0.0f;
    int cur = -1;
    for (int j = 0; j < cntN; ++j) {
        int node = __shfl(mm, j, 64);
        int sg = __shfl(sgv, j, 64);
        float sc = __shfl(wv0, j, 64) / __shfl(zz0, j, 64);
        if (sg != cur) {
            if (cur >= 0) {
                float* pr = out_pooled + (size_t)cur * C;
                atomicAdd(&pr[lane], a0);
                if (has1) atomicAdd(&pr[c1], a1);
            }
            cur = sg;
            a0 = a1 = 0.0f;
        }
        if (lane == 0) out_scaling[node] = sc;
        const float* xr = x + (size_t)node * C;
        a0 += xr[lane] * sc;
        if (has1) a1 += xr[c1] * sc;
    }
    float* pr = out_pooled + (size_t)cur * C;
    atomicAdd(&pr[lane], a0);
    if (has1) atomicAdd(&pr[c1], a1);
}

extern "C" void kernel_launch(void* const* d_in, const int* in_sizes, int n_in,
                              void* d_out, int out_size, void* d_ws, size_t ws_size,
                              hipStream_t stream) {
    const float* x = (const float*)d_in[0];
    const float* W = (const float*)d_in[1];
    const float* b = (const float*)d_in[2];
    const int* ei = (const int*)d_in[3];
    const int* batch = (const int*)d_in[4];

    const int C = in_sizes[1];           // 128
    const int N = in_sizes[0] / C;       // 100000
    const int E = in_sizes[3] / 2;       // 3200000
    const int Eh = E / 2;                // 1600000 undirected pairs

    float* out_pooled   = (float*)d_out;
    float* out_seg      = out_pooled + (size_t)N * C;
    float* out_scaling  = out_seg + N;
    float* out_cb       = out_scaling + N;
    float* out_ispeak   = out_cb + N;
    float* out_istrough = out_ispeak + N;

    char* p = (char*)d_ws;
    auto alloc = [&](size_t bytes) -> char* {
        char* r = p;
        p += (bytes + 255) & ~(size_t)255;
        return r;
    };
    double* elev64 = (double*)alloc((size_t)N * 8);
    float* elev32  = (float*)alloc((size_t)N * 4);
    int* best      = (int*)alloc((size_t)N * 4);
    int* bsnap     = (int*)alloc((size_t)N * 4);
    int* peakflag  = (int*)alloc((size_t)N * 4);
    int* new_id    = (int*)alloc((size_t)N * 4);
    int* seg       = (int*)alloc((size_t)N * 4);
    float* wbuf    = (float*)alloc((size_t)N * 4);
    int* members   = (int*)alloc((size_t)N * 4);
    int* cstart    = (int*)alloc((size_t)N * 4);
    int* cursor8   = (int*)alloc((size_t)N * 4 * 8);
    float* z       = (float*)alloc((size_t)N * 4);
    unsigned char* rnd  = (unsigned char*)alloc((size_t)N);
    unsigned char* rnd2 = (unsigned char*)alloc((size_t)N);
    const int P = (N + 255) / 256;
    int* part = (int*)alloc((size_t)P * 4);
    int* offs = (int*)alloc((size_t)P * 4);
    unsigned char* code = (unsigned char*)alloc((size_t)Eh);
    char* zbeg = p;  // zero-initialized region starts here
    unsigned char* notpeak   = (unsigned char*)alloc((size_t)N);
    unsigned char* nottrough = (unsigned char*)alloc((size_t)N);
    int* hist8 = (int*)alloc((size_t)N * 4 * 8);
    int* dcnt  = (int*)alloc(2048 * 4);
    size_t zspan = (size_t)(p - zbeg);
    int2* down0 = (int2*)alloc((size_t)E * 8);
    int2* down1 = (int2*)alloc((size_t)E * 8);
    int* Kptr = dcnt + 1024;
    (void)ws_size;

    // fast zero of out_pooled (N*C floats) + workspace zero-region
    k_zero<<<2048, 256, 0, stream>>>((float4*)out_pooled,
                                     (size_t)N * C / 4,
                                     (float4*)zbeg, zspan / 16);

    const int B4 = (Eh + 1023) / 1024;   // 4 pairs per thread
    const int B8 = (Eh + 2047) / 2048;   // 8 pairs per thread

    k_matvec<<<(N + 3) / 4, 256, 0, stream>>>(x, W, b, elev64, elev32, N, C);
    k_mark<<<B4, 256, 0, stream>>>(ei, elev64, elev32, notpeak, nottrough,
                                   code, Eh, E);
    k_nodes1<<<P, 256, 0, stream>>>(notpeak, nottrough, peakflag, best, rnd,
                                    out_ispeak, out_istrough, out_cb, part, N);
    k_scan_offs<<<1, 64, 0, stream>>>(part, offs, P);

    k_build_l1<<<B8, 256, 0, stream>>>(ei, code, notpeak, best, rnd, Eh, E);
    k_scan_final0<<<P, 256, 0, stream>>>(peakflag, offs, best, rnd, new_id,
                                         bsnap, rnd2, Kptr, N);
    k_sweep2<<<B8, 256, 0, stream>>>(ei, code, bsnap, rnd2, best, rnd,
                                     down0, dcnt, Eh, E);

    for (int L = 3; L <= NLEVELS; ++L)
        k_level_e<<<2048, 256, 0, stream>>>(down0, down1, dcnt, best, rnd, L);
    k_tail_e<<<1, 1024, 0, stream>>>(down0, down1, dcnt, best);

    k_segw2<<<P, 256, 0, stream>>>(best, new_id, elev32, batch, seg, out_seg,
                                   out_cb, wbuf, hist8, N);
    k_scan_part_h<<<P, 256, 0, stream>>>(hist8, part, N);
    k_scan_offs<<<1, 64, 0, stream>>>(part, offs, P);
    k_scan_final_h<<<P, 256, 0, stream>>>(hist8, offs, cstart, cursor8, N);
    k_cfill2<<<P, 256, 0, stream>>>(seg, cursor8, members, N);
    k_zsum<<<128, 256, 0, stream>>>(members, cstart, wbuf, Kptr, z, N);

    const int NW = (N + POOLM - 1) / POOLM;
    k_pool_seg<<<(NW + 3) / 4, 256, 0, stream>>>(x, members, seg, wbuf, z,
                                                 out_scaling, out_pooled, N, C);
}